// Round 1
// baseline (268.485 us; speedup 1.0000x reference)
//
#include <hip/hip_runtime.h>
#include <hip/hip_bf16.h>
#include <cstdint>

// ---------------------------------------------------------------------------
// LocalMultiHeadAttention: B=2, T=1024, D=1024, H=16, dh=64, band=65 (half 32)
// Pipeline:
//   1. cvt x, context -> bf16
//   2. transpose+cvt W_q|W_k|W_v -> Wqkvt[N=3072][K=1024] bf16, W_out -> Wot
//   3. GEMM (bf16 MFMA 16x16x32, 128x128 tile, BK=64, global_load_lds w16):
//        Q = Xb @ Wq^T  (cols 0..1023 of QKVb, ld 3072)
//        K,V = Cb @ [Wk|Wv]^T (cols 1024..3071)
//   4. band attention: 1 wave per (b,h,i); score = q.(k + L[j-i+1023]) * 0.125
//      online softmax; ctx -> bf16 [2048][1024]
//   5. GEMM: OutB = CtxB @ Wot^T (bf16)
//   6. LN: y = LayerNorm(x + OutB + b_out) -> f32
// ---------------------------------------------------------------------------

typedef __bf16 bf16x8 __attribute__((ext_vector_type(8)));
typedef __bf16 bf16x4 __attribute__((ext_vector_type(4)));
typedef float f32x4 __attribute__((ext_vector_type(4)));

#define GLD_LDS(gptr, lptr)                                                    \
  __builtin_amdgcn_global_load_lds(                                            \
      (const __attribute__((address_space(1))) void*)(gptr),                   \
      (__attribute__((address_space(3))) void*)(lptr), 16, 0, 0)

// ---------------- 1. f32 -> bf16 convert (vectorized) ----------------------
__global__ __launch_bounds__(256) void cvt_f32_bf16(
    const float* __restrict__ in, __bf16* __restrict__ out, int n4) {
  int i = blockIdx.x * 256 + threadIdx.x;
  if (i < n4) {
    float4 v = ((const float4*)in)[i];
    bf16x4 o;
    o[0] = (__bf16)v.x; o[1] = (__bf16)v.y; o[2] = (__bf16)v.z; o[3] = (__bf16)v.w;
    ((bf16x4*)out)[i] = o;
  }
}

// ---------------- 2. transpose + convert (1024x1024 f32 -> bf16^T) ---------
__global__ __launch_bounds__(256) void transpose_cvt(
    const float* __restrict__ W, __bf16* __restrict__ Wt) {
  __shared__ float tile[64][65];
  const int k0 = blockIdx.x * 64, n0 = blockIdx.y * 64;
  const int tx = threadIdx.x & 63, ty = threadIdx.x >> 6;  // ty in 0..3
#pragma unroll
  for (int r = ty; r < 64; r += 4)
    tile[r][tx] = W[(size_t)(k0 + r) * 1024 + n0 + tx];
  __syncthreads();
#pragma unroll
  for (int r = ty; r < 64; r += 4)
    Wt[(size_t)(n0 + r) * 1024 + k0 + tx] = (__bf16)tile[tx][r];
}

// ---------------- 3/5. bf16 GEMM: C[M][N](ld=ldc) = A[M][K] * Bt[N][K]^T ----
// 128x128 tile, BK=64, 256 threads (4 waves, 2x2), mfma_f32_16x16x32_bf16.
__global__ __launch_bounds__(256) void gemm_bf16(
    const __bf16* __restrict__ A, const __bf16* __restrict__ Bt,
    __bf16* __restrict__ C, int M, int N, int K, int ldc) {
  __shared__ alignas(16) __bf16 As[128 * 64];
  __shared__ alignas(16) __bf16 Bs[128 * 64];
  const int tid = threadIdx.x;
  const int m0 = blockIdx.y * 128, n0 = blockIdx.x * 128;
  const int w = tid >> 6, lane = tid & 63;
  const int wr = w >> 1, wc = w & 1;
  const int lrow = lane & 15, lk = (lane >> 4) * 8;

  f32x4 acc[4][4] = {};

  for (int kt = 0; kt < K; kt += 64) {
    __syncthreads();
#pragma unroll
    for (int it = 0; it < 4; ++it) {
      const int c = it * 256 + tid;          // 0..1023 chunk id (16B each)
      const int row = c >> 3;                // 0..127
      const int ko = (c & 7) * 8;            // 0..56
      GLD_LDS(A + (size_t)(m0 + row) * K + kt + ko, As + c * 8);
      GLD_LDS(Bt + (size_t)(n0 + row) * K + kt + ko, Bs + c * 8);
    }
    __syncthreads();
#pragma unroll
    for (int ks = 0; ks < 64; ks += 32) {
      bf16x8 av[4], bv[4];
#pragma unroll
      for (int mi = 0; mi < 4; ++mi)
        av[mi] = *(const bf16x8*)&As[(wr * 64 + mi * 16 + lrow) * 64 + ks + lk];
#pragma unroll
      for (int ni = 0; ni < 4; ++ni)
        bv[ni] = *(const bf16x8*)&Bs[(wc * 64 + ni * 16 + lrow) * 64 + ks + lk];
#pragma unroll
      for (int mi = 0; mi < 4; ++mi)
#pragma unroll
        for (int ni = 0; ni < 4; ++ni)
          acc[mi][ni] = __builtin_amdgcn_mfma_f32_16x16x32_bf16(
              av[mi], bv[ni], acc[mi][ni], 0, 0, 0);
    }
  }

  // epilogue: D col = lane&15, row = (lane>>4)*4 + r  [m89/m91 verified]
  const int rbase = m0 + wr * 64 + (lane >> 4) * 4;
  const int cbase = n0 + wc * 64 + (lane & 15);
#pragma unroll
  for (int mi = 0; mi < 4; ++mi)
#pragma unroll
    for (int ni = 0; ni < 4; ++ni)
#pragma unroll
      for (int r = 0; r < 4; ++r)
        C[(size_t)(rbase + mi * 16 + r) * ldc + cbase + ni * 16] =
            (__bf16)acc[mi][ni][r];
}

// ---------------- 4. band attention (1 wave per (b,h,i), lane = d) ---------
__global__ __launch_bounds__(256) void attn_band(
    const __bf16* __restrict__ QKV,  // [2048][3072]: Q | K | V
    const float* __restrict__ lut,   // [2047][64]
    __bf16* __restrict__ Ctx) {      // [2048][1024]
  const int wid = blockIdx.x * 4 + (threadIdx.x >> 6);
  const int lane = threadIdx.x & 63;
  const int i = wid & 1023;
  const int h = (wid >> 10) & 15;
  const int b = wid >> 14;

  const size_t rowq = (size_t)(b * 1024 + i) * 3072 + h * 64;
  const float qd = (float)QKV[rowq + lane];

  float m = -1e30f, l = 0.f, accd = 0.f;
  const int jlo = (i - 32 < 0) ? 0 : i - 32;
  const int jhi = (i + 32 > 1023) ? 1023 : i + 32;
  for (int j = jlo; j <= jhi; ++j) {
    const int jj = j - i + 32;  // 0..64
    const size_t rowk = (size_t)(b * 1024 + j) * 3072 + 1024 + h * 64;
    const float kd = (float)QKV[rowk + lane];
    const float ld = lut[(size_t)(jj + 991) * 64 + lane];
    float s = qd * (kd + ld);
#pragma unroll
    for (int off = 32; off; off >>= 1) s += __shfl_xor(s, off);
    s *= 0.125f;
    const float mn = fmaxf(m, s);
    const float corr = __expf(m - mn);
    const float p = __expf(s - mn);
    const float vd = (float)QKV[rowk + 1024 + lane];
    l = l * corr + p;
    accd = accd * corr + p * vd;
    m = mn;
  }
  Ctx[(size_t)(b * 1024 + i) * 1024 + h * 64 + lane] = (__bf16)(accd / l);
}

// ---------------- 6. residual + bias + LayerNorm ---------------------------
__global__ __launch_bounds__(256) void ln_residual(
    const float* __restrict__ x, const __bf16* __restrict__ outb,
    const float* __restrict__ bout, const float* __restrict__ gamma,
    const float* __restrict__ beta, float* __restrict__ y) {
  const int r = blockIdx.x;
  const int tid = threadIdx.x;
  float v[4];
  float s = 0.f, ss = 0.f;
#pragma unroll
  for (int it = 0; it < 4; ++it) {
    const int d = it * 256 + tid;
    const float t = x[(size_t)r * 1024 + d] + (float)outb[(size_t)r * 1024 + d] + bout[d];
    v[it] = t;
    s += t;
    ss += t * t;
  }
#pragma unroll
  for (int off = 32; off; off >>= 1) {
    s += __shfl_xor(s, off);
    ss += __shfl_xor(ss, off);
  }
  __shared__ float red[8];
  const int w = tid >> 6, lane = tid & 63;
  if (lane == 0) { red[w] = s; red[4 + w] = ss; }
  __syncthreads();
  s = red[0] + red[1] + red[2] + red[3];
  ss = red[4] + red[5] + red[6] + red[7];
  const float mu = s * (1.f / 1024.f);
  const float var = ss * (1.f / 1024.f) - mu * mu;
  const float rs = rsqrtf(var + 1e-5f);
#pragma unroll
  for (int it = 0; it < 4; ++it) {
    const int d = it * 256 + tid;
    y[(size_t)r * 1024 + d] = (v[it] - mu) * rs * gamma[d] + beta[d];
  }
}

// ---------------------------------------------------------------------------
extern "C" void kernel_launch(void* const* d_in, const int* in_sizes, int n_in,
                              void* d_out, int out_size, void* d_ws, size_t ws_size,
                              hipStream_t stream) {
  const float* x     = (const float*)d_in[0];
  const float* ctxin = (const float*)d_in[1];
  const float* lut   = (const float*)d_in[2];
  const float* Wq    = (const float*)d_in[3];
  const float* Wk    = (const float*)d_in[4];
  const float* Wv    = (const float*)d_in[5];
  const float* Wo    = (const float*)d_in[6];
  const float* bo    = (const float*)d_in[7];
  const float* gam   = (const float*)d_in[8];
  const float* bet   = (const float*)d_in[9];
  float* out = (float*)d_out;

  char* ws = (char*)d_ws;
  __bf16* Xb    = (__bf16*)(ws);                        // 4 MB  [2048][1024]
  __bf16* Cb    = (__bf16*)(ws + ((size_t)4 << 20));    // 4 MB  [2048][1024]
  __bf16* Wqkvt = (__bf16*)(ws + ((size_t)8 << 20));    // 6 MB  [3072][1024]
  __bf16* Wot   = (__bf16*)(ws + ((size_t)14 << 20));   // 2 MB  [1024][1024]
  __bf16* QKVb  = (__bf16*)(ws + ((size_t)16 << 20));   // 12 MB [2048][3072]
  __bf16* CtxB  = (__bf16*)(ws + ((size_t)28 << 20));   // 4 MB  [2048][1024]
  __bf16* OutB  = (__bf16*)(ws + ((size_t)32 << 20));   // 4 MB  [2048][1024]

  // 1. converts (2M f32 each -> 524288 float4 chunks)
  cvt_f32_bf16<<<2048, 256, 0, stream>>>(x, Xb, 524288);
  cvt_f32_bf16<<<2048, 256, 0, stream>>>(ctxin, Cb, 524288);

  // 2. weight transposes
  dim3 tg(16, 16);
  transpose_cvt<<<tg, 256, 0, stream>>>(Wq, Wqkvt);
  transpose_cvt<<<tg, 256, 0, stream>>>(Wk, Wqkvt + (size_t)1024 * 1024);
  transpose_cvt<<<tg, 256, 0, stream>>>(Wv, Wqkvt + (size_t)2 * 1024 * 1024);
  transpose_cvt<<<tg, 256, 0, stream>>>(Wo, Wot);

  // 3. projections
  gemm_bf16<<<dim3(8, 16), 256, 0, stream>>>(Xb, Wqkvt, QKVb, 2048, 1024, 1024, 3072);
  gemm_bf16<<<dim3(16, 16), 256, 0, stream>>>(Cb, Wqkvt + (size_t)1024 * 1024,
                                              QKVb + 1024, 2048, 2048, 1024, 3072);

  // 4. band attention
  attn_band<<<8192, 256, 0, stream>>>(QKVb, lut, CtxB);

  // 5. output projection
  gemm_bf16<<<dim3(8, 16), 256, 0, stream>>>(CtxB, Wot, OutB, 2048, 1024, 1024, 1024);

  // 6. residual + bias + layernorm
  ln_residual<<<2048, 256, 0, stream>>>(x, OutB, bo, gam, bet, out);
}

// Round 2
// 174.704 us; speedup vs baseline: 1.5368x; 1.5368x over previous
//
#include <hip/hip_runtime.h>
#include <hip/hip_bf16.h>
#include <cstdint>

// ---------------------------------------------------------------------------
// LocalMultiHeadAttention: B=2, T=1024, D=1024, H=16, dh=64, band=65 (half 32)
// Pipeline:
//   1. cvt x, context -> bf16
//   2. transpose+cvt W_q|W_k|W_v -> Wqkvt[N=3072][K=1024] bf16, W_out -> Wot
//   3. GEMM (bf16 MFMA 16x16x32, 128x128 tile, BK=64, global_load_lds w16)
//   4. band attention v2: wave-parallel over keys (lane = rel key r)
//   5. GEMM: OutB = CtxB @ Wot^T (bf16)
//   6. LN: y = LayerNorm(x + OutB + b_out) -> f32
// ---------------------------------------------------------------------------

typedef __bf16 bf16x8 __attribute__((ext_vector_type(8)));
typedef __bf16 bf16x4 __attribute__((ext_vector_type(4)));
typedef float f32x4 __attribute__((ext_vector_type(4)));

#define GLD_LDS(gptr, lptr)                                                    \
  __builtin_amdgcn_global_load_lds(                                            \
      (const __attribute__((address_space(1))) void*)(gptr),                   \
      (__attribute__((address_space(3))) void*)(lptr), 16, 0, 0)

// ---------------- 1. f32 -> bf16 convert (vectorized) ----------------------
__global__ __launch_bounds__(256) void cvt_f32_bf16(
    const float* __restrict__ in, __bf16* __restrict__ out, int n4) {
  int i = blockIdx.x * 256 + threadIdx.x;
  if (i < n4) {
    float4 v = ((const float4*)in)[i];
    bf16x4 o;
    o[0] = (__bf16)v.x; o[1] = (__bf16)v.y; o[2] = (__bf16)v.z; o[3] = (__bf16)v.w;
    ((bf16x4*)out)[i] = o;
  }
}

// ---------------- 2. transpose + convert (1024x1024 f32 -> bf16^T) ---------
__global__ __launch_bounds__(256) void transpose_cvt(
    const float* __restrict__ W, __bf16* __restrict__ Wt) {
  __shared__ float tile[64][65];
  const int k0 = blockIdx.x * 64, n0 = blockIdx.y * 64;
  const int tx = threadIdx.x & 63, ty = threadIdx.x >> 6;  // ty in 0..3
#pragma unroll
  for (int r = ty; r < 64; r += 4)
    tile[r][tx] = W[(size_t)(k0 + r) * 1024 + n0 + tx];
  __syncthreads();
#pragma unroll
  for (int r = ty; r < 64; r += 4)
    Wt[(size_t)(n0 + r) * 1024 + k0 + tx] = (__bf16)tile[tx][r];
}

// ---------------- 3/5. bf16 GEMM: C[M][N](ld=ldc) = A[M][K] * Bt[N][K]^T ----
__global__ __launch_bounds__(256) void gemm_bf16(
    const __bf16* __restrict__ A, const __bf16* __restrict__ Bt,
    __bf16* __restrict__ C, int M, int N, int K, int ldc) {
  __shared__ alignas(16) __bf16 As[128 * 64];
  __shared__ alignas(16) __bf16 Bs[128 * 64];
  const int tid = threadIdx.x;
  const int m0 = blockIdx.y * 128, n0 = blockIdx.x * 128;
  const int w = tid >> 6, lane = tid & 63;
  const int wr = w >> 1, wc = w & 1;
  const int lrow = lane & 15, lk = (lane >> 4) * 8;

  f32x4 acc[4][4] = {};

  for (int kt = 0; kt < K; kt += 64) {
    __syncthreads();
#pragma unroll
    for (int it = 0; it < 4; ++it) {
      const int c = it * 256 + tid;          // 0..1023 chunk id (16B each)
      const int row = c >> 3;                // 0..127
      const int ko = (c & 7) * 8;            // 0..56
      GLD_LDS(A + (size_t)(m0 + row) * K + kt + ko, As + c * 8);
      GLD_LDS(Bt + (size_t)(n0 + row) * K + kt + ko, Bs + c * 8);
    }
    __syncthreads();
#pragma unroll
    for (int ks = 0; ks < 64; ks += 32) {
      bf16x8 av[4], bv[4];
#pragma unroll
      for (int mi = 0; mi < 4; ++mi)
        av[mi] = *(const bf16x8*)&As[(wr * 64 + mi * 16 + lrow) * 64 + ks + lk];
#pragma unroll
      for (int ni = 0; ni < 4; ++ni)
        bv[ni] = *(const bf16x8*)&Bs[(wc * 64 + ni * 16 + lrow) * 64 + ks + lk];
#pragma unroll
      for (int mi = 0; mi < 4; ++mi)
#pragma unroll
        for (int ni = 0; ni < 4; ++ni)
          acc[mi][ni] = __builtin_amdgcn_mfma_f32_16x16x32_bf16(
              av[mi], bv[ni], acc[mi][ni], 0, 0, 0);
    }
  }

  const int rbase = m0 + wr * 64 + (lane >> 4) * 4;
  const int cbase = n0 + wc * 64 + (lane & 15);
#pragma unroll
  for (int mi = 0; mi < 4; ++mi)
#pragma unroll
    for (int ni = 0; ni < 4; ++ni)
#pragma unroll
      for (int r = 0; r < 4; ++r)
        C[(size_t)(rbase + mi * 16 + r) * ldc + cbase + ni * 16] =
            (__bf16)acc[mi][ni][r];
}

// ---------------- 4. band attention v2 -------------------------------------
// Block = (iblock of 32, h, b); 256 threads = 4 waves; wave owns 8 queries.
// Score phase: lane = relative key r (0..63), no per-key cross-lane reduce.
// K/L staged f32 in LDS, XOR-swizzled at f32-pair granularity so the
// 64-consecutive-row column read (stride 64 f32 = all-same-bank) spreads.
// Tap r=64 handled with one lane=d partial + 6-shfl reduce per query.
__global__ __launch_bounds__(256) void attn_band_v2(
    const __bf16* __restrict__ QKV,  // [2048][3072]: Q | K | V
    const float* __restrict__ lut,   // [2047][64]
    __bf16* __restrict__ Ctx) {      // [2048][1024]
  __shared__ float Qs[32 * 64];   // [32][64] linear (broadcast reads)
  __shared__ float Ks[96 * 64];   // [96][64] pair-swizzled: d2 ^= (row&15)
  __shared__ float Ls[65 * 64];   // [65][64] pair-swizzled: d2 ^= (row&15)
  __shared__ float Vs[96 * 64];   // [96][64] linear (row-broadcast reads)

  const int tid = threadIdx.x;
  const int i0 = blockIdx.x * 32;
  const int h = blockIdx.y;
  const int b = blockIdx.z;
  const size_t base = (size_t)b * 1024 * 3072 + (size_t)h * 64;

  // ---- staging ----
  {  // Q: 32 rows x 8 chunks = 256 chunks, one per thread
    const int row = tid >> 3, d0 = (tid & 7) * 8;
    bf16x8 v = *(const bf16x8*)(QKV + base + (size_t)(i0 + row) * 3072 + d0);
#pragma unroll
    for (int e = 0; e < 8; ++e) Qs[row * 64 + d0 + e] = (float)v[e];
  }
  for (int c = tid; c < 96 * 8; c += 256) {  // K (swizzled f32 pairs)
    const int kl = c >> 3, d0 = (c & 7) * 8;
    int j = i0 - 32 + kl;
    j = j < 0 ? 0 : (j > 1023 ? 1023 : j);
    bf16x8 v = *(const bf16x8*)(QKV + base + (size_t)j * 3072 + 1024 + d0);
#pragma unroll
    for (int e = 0; e < 8; e += 2) {
      const int d2s = (((d0 + e) >> 1) ^ (kl & 15)) * 2;
      *(float2*)&Ks[kl * 64 + d2s] = make_float2((float)v[e], (float)v[e + 1]);
    }
  }
  for (int c = tid; c < 96 * 8; c += 256) {  // V (linear)
    const int kl = c >> 3, d0 = (c & 7) * 8;
    int j = i0 - 32 + kl;
    j = j < 0 ? 0 : (j > 1023 ? 1023 : j);
    bf16x8 v = *(const bf16x8*)(QKV + base + (size_t)j * 3072 + 2048 + d0);
#pragma unroll
    for (int e = 0; e < 8; ++e) Vs[kl * 64 + d0 + e] = (float)v[e];
  }
  for (int c = tid; c < 65 * 8; c += 256) {  // L rows 991..1055 (swizzled)
    const int r = c >> 3, d0 = (c & 7) * 8;
    const float* src = lut + (size_t)(991 + r) * 64 + d0;
#pragma unroll
    for (int e = 0; e < 8; e += 2) {
      const int d2s = (((d0 + e) >> 1) ^ (r & 15)) * 2;
      *(float2*)&Ls[r * 64 + d2s] = make_float2(src[e], src[e + 1]);
    }
  }
  __syncthreads();

  const int w = tid >> 6, lane = tid & 63;
  const int lxor = (lane & 15);  // L-row swizzle key for row==lane (&15)

  for (int sub = 0; sub < 8; ++sub) {
    const int lq = w * 8 + sub;
    const int i = i0 + lq;

    // query row into registers (broadcast b64 reads)
    float2 qreg[32];
#pragma unroll
    for (int d2 = 0; d2 < 32; ++d2)
      qreg[d2] = *(const float2*)&Qs[lq * 64 + d2 * 2];

    // ---- scores: lane r in [0,63] ----
    const int kl = lq + lane;
    const int kxor = kl & 15;
    float s = 0.f;
#pragma unroll
    for (int d2 = 0; d2 < 32; ++d2) {
      const float2 kp = *(const float2*)&Ks[kl * 64 + (d2 ^ kxor) * 2];
      const float2 lp = *(const float2*)&Ls[lane * 64 + (d2 ^ lxor) * 2];
      s += qreg[d2].x * (kp.x + lp.x) + qreg[d2].y * (kp.y + lp.y);
    }

    // ---- tap r=64 (lane = d partial, reduce) ----
    const int kl64 = lq + 64;
    const int e64 = (((lane >> 1) ^ (kl64 & 15)) << 1) + (lane & 1);
    const int el64 = (((lane >> 1) ^ 0) << 1) + (lane & 1);  // row 64: &15 == 0
    float part = Qs[lq * 64 + lane] * (Ks[kl64 * 64 + e64] + Ls[64 * 64 + el64]);
#pragma unroll
    for (int off = 32; off; off >>= 1) part += __shfl_xor(part, off);
    float s64 = part;

    // ---- mask + softmax ----
    const int j = i + lane - 32;
    if (j < 0 || j > 1023) s = -1e30f;
    if (i + 32 > 1023) s64 = -1e30f;
    s *= 0.125f;
    s64 *= 0.125f;
    float m = fmaxf(s, s64);
#pragma unroll
    for (int off = 32; off; off >>= 1) m = fmaxf(m, __shfl_xor(m, off));
    const float p = __expf(s - m);
    const float p64 = __expf(s64 - m);  // uniform
    float l = p;
#pragma unroll
    for (int off = 32; off; off >>= 1) l += __shfl_xor(l, off);
    l += p64;

    // ---- PV: lane = d ----
    float acc = 0.f;
#pragma unroll
    for (int r = 0; r < 64; ++r) {
      const float pb = __shfl(p, r);
      acc = fmaf(pb, Vs[(lq + r) * 64 + lane], acc);
    }
    acc = fmaf(p64, Vs[(lq + 64) * 64 + lane], acc);

    Ctx[(size_t)(b * 1024 + i) * 1024 + h * 64 + lane] = (__bf16)(acc / l);
  }
}

// ---------------- 6. residual + bias + LayerNorm ---------------------------
__global__ __launch_bounds__(256) void ln_residual(
    const float* __restrict__ x, const __bf16* __restrict__ outb,
    const float* __restrict__ bout, const float* __restrict__ gamma,
    const float* __restrict__ beta, float* __restrict__ y) {
  const int r = blockIdx.x;
  const int tid = threadIdx.x;
  float v[4];
  float s = 0.f, ss = 0.f;
#pragma unroll
  for (int it = 0; it < 4; ++it) {
    const int d = it * 256 + tid;
    const float t = x[(size_t)r * 1024 + d] + (float)outb[(size_t)r * 1024 + d] + bout[d];
    v[it] = t;
    s += t;
    ss += t * t;
  }
#pragma unroll
  for (int off = 32; off; off >>= 1) {
    s += __shfl_xor(s, off);
    ss += __shfl_xor(ss, off);
  }
  __shared__ float red[8];
  const int w = tid >> 6, lane = tid & 63;
  if (lane == 0) { red[w] = s; red[4 + w] = ss; }
  __syncthreads();
  s = red[0] + red[1] + red[2] + red[3];
  ss = red[4] + red[5] + red[6] + red[7];
  const float mu = s * (1.f / 1024.f);
  const float var = ss * (1.f / 1024.f) - mu * mu;
  const float rs = rsqrtf(var + 1e-5f);
#pragma unroll
  for (int it = 0; it < 4; ++it) {
    const int d = it * 256 + tid;
    y[(size_t)r * 1024 + d] = (v[it] - mu) * rs * gamma[d] + beta[d];
  }
}

// ---------------------------------------------------------------------------
extern "C" void kernel_launch(void* const* d_in, const int* in_sizes, int n_in,
                              void* d_out, int out_size, void* d_ws, size_t ws_size,
                              hipStream_t stream) {
  const float* x     = (const float*)d_in[0];
  const float* ctxin = (const float*)d_in[1];
  const float* lut   = (const float*)d_in[2];
  const float* Wq    = (const float*)d_in[3];
  const float* Wk    = (const float*)d_in[4];
  const float* Wv    = (const float*)d_in[5];
  const float* Wo    = (const float*)d_in[6];
  const float* bo    = (const float*)d_in[7];
  const float* gam   = (const float*)d_in[8];
  const float* bet   = (const float*)d_in[9];
  float* out = (float*)d_out;

  char* ws = (char*)d_ws;
  __bf16* Xb    = (__bf16*)(ws);                        // 4 MB  [2048][1024]
  __bf16* Cb    = (__bf16*)(ws + ((size_t)4 << 20));    // 4 MB  [2048][1024]
  __bf16* Wqkvt = (__bf16*)(ws + ((size_t)8 << 20));    // 6 MB  [3072][1024]
  __bf16* Wot   = (__bf16*)(ws + ((size_t)14 << 20));   // 2 MB  [1024][1024]
  __bf16* QKVb  = (__bf16*)(ws + ((size_t)16 << 20));   // 12 MB [2048][3072]
  __bf16* CtxB  = (__bf16*)(ws + ((size_t)28 << 20));   // 4 MB  [2048][1024]
  __bf16* OutB  = (__bf16*)(ws + ((size_t)32 << 20));   // 4 MB  [2048][1024]

  cvt_f32_bf16<<<2048, 256, 0, stream>>>(x, Xb, 524288);
  cvt_f32_bf16<<<2048, 256, 0, stream>>>(ctxin, Cb, 524288);

  dim3 tg(16, 16);
  transpose_cvt<<<tg, 256, 0, stream>>>(Wq, Wqkvt);
  transpose_cvt<<<tg, 256, 0, stream>>>(Wk, Wqkvt + (size_t)1024 * 1024);
  transpose_cvt<<<tg, 256, 0, stream>>>(Wv, Wqkvt + (size_t)2 * 1024 * 1024);
  transpose_cvt<<<tg, 256, 0, stream>>>(Wo, Wot);

  gemm_bf16<<<dim3(8, 16), 256, 0, stream>>>(Xb, Wqkvt, QKVb, 2048, 1024, 1024, 3072);
  gemm_bf16<<<dim3(16, 16), 256, 0, stream>>>(Cb, Wqkvt + (size_t)1024 * 1024,
                                              QKVb + 1024, 2048, 2048, 1024, 3072);

  attn_band_v2<<<dim3(32, 16, 2), 256, 0, stream>>>(QKVb, lut, CtxB);

  gemm_bf16<<<dim3(8, 16), 256, 0, stream>>>(CtxB, Wot, OutB, 2048, 1024, 1024, 1024);

  ln_residual<<<2048, 256, 0, stream>>>(x, OutB, bo, gam, bet, out);
}

// Round 3
// 87.029 us; speedup vs baseline: 3.0850x; 2.0074x over previous
//
#include <hip/hip_runtime.h>
#include <hip/hip_bf16.h>
#include <cstdint>

// ---------------------------------------------------------------------------
// LocalMultiHeadAttention: B=2, T=1024, D=1024, H=16, dh=64, band=65 (half 32)
//   1. cvt2: x, context -> bf16 (one dispatch)
//   2. transpose4: W_q|W_k|W_v -> Wqkvt[3072][1024], W_out -> Wot (one dispatch)
//   3. gemm (fused): QKVb[2048][3072] = {Xb@Wq^T | Cb@Wk^T | Cb@Wv^T}
//   4. attn v3: MFMA flash-style band attention, skew via QE=Q@L^T GEMM
//   5. gemm: OutB = CtxB @ Wot^T
//   6. LN: y = LayerNorm(x + OutB + b_out)
// ---------------------------------------------------------------------------

typedef __bf16 bf16x8 __attribute__((ext_vector_type(8)));
typedef __bf16 bf16x4 __attribute__((ext_vector_type(4)));
typedef float f32x4 __attribute__((ext_vector_type(4)));

#define GLD_LDS(gptr, lptr)                                                    \
  __builtin_amdgcn_global_load_lds(                                            \
      (const __attribute__((address_space(1))) void*)(gptr),                   \
      (__attribute__((address_space(3))) void*)(lptr), 16, 0, 0)

// ---------------- 1. f32 -> bf16 convert (x and context fused) -------------
__global__ __launch_bounds__(256) void cvt2_f32_bf16(
    const float* __restrict__ x, const float* __restrict__ c,
    __bf16* __restrict__ X, __bf16* __restrict__ C) {
  const float* in = blockIdx.y ? c : x;
  __bf16* out = blockIdx.y ? C : X;
  const int i = blockIdx.x * 256 + threadIdx.x;  // 2048*256 == 524288 exactly
  float4 v = ((const float4*)in)[i];
  bf16x4 o;
  o[0] = (__bf16)v.x; o[1] = (__bf16)v.y; o[2] = (__bf16)v.z; o[3] = (__bf16)v.w;
  ((bf16x4*)out)[i] = o;
}

// ---------------- 2. transpose + convert, all 4 weights fused --------------
__global__ __launch_bounds__(256) void transpose4_cvt(
    const float* __restrict__ Wq, const float* __restrict__ Wk,
    const float* __restrict__ Wv, const float* __restrict__ Wo,
    __bf16* __restrict__ Wqkvt, __bf16* __restrict__ Wot) {
  const int z = blockIdx.z;
  const float* W = z == 0 ? Wq : z == 1 ? Wk : z == 2 ? Wv : Wo;
  __bf16* Wt = (z == 3) ? Wot : Wqkvt + (size_t)z * 1024 * 1024;
  __shared__ float tile[64][65];
  const int k0 = blockIdx.x * 64, n0 = blockIdx.y * 64;
  const int tx = threadIdx.x & 63, ty = threadIdx.x >> 6;
#pragma unroll
  for (int r = ty; r < 64; r += 4)
    tile[r][tx] = W[(size_t)(k0 + r) * 1024 + n0 + tx];
  __syncthreads();
#pragma unroll
  for (int r = ty; r < 64; r += 4)
    Wt[(size_t)(n0 + r) * 1024 + k0 + tx] = (__bf16)tile[tx][r];
}

// ---------------- 3/5. bf16 GEMM: C = A(n-block selected) * Bt^T -----------
// 128x128 tile, BK=64, 4 waves, mfma 16x16x32. A = (n0<nsplit) ? A0 : A1.
__global__ __launch_bounds__(256) void gemm_bf16(
    const __bf16* __restrict__ A0, const __bf16* __restrict__ A1, int nsplit,
    const __bf16* __restrict__ Bt, __bf16* __restrict__ C,
    int K, int ldc) {
  __shared__ alignas(16) __bf16 As[128 * 64];
  __shared__ alignas(16) __bf16 Bs[128 * 64];
  const int tid = threadIdx.x;
  const int m0 = blockIdx.y * 128, n0 = blockIdx.x * 128;
  const __bf16* A = (n0 < nsplit) ? A0 : A1;
  const int w = tid >> 6, lane = tid & 63;
  const int wr = w >> 1, wc = w & 1;
  const int lrow = lane & 15, lk = (lane >> 4) * 8;

  f32x4 acc[4][4] = {};

  for (int kt = 0; kt < K; kt += 64) {
    __syncthreads();
#pragma unroll
    for (int it = 0; it < 4; ++it) {
      const int c = it * 256 + tid;
      const int row = c >> 3;
      const int ko = (c & 7) * 8;
      GLD_LDS(A + (size_t)(m0 + row) * K + kt + ko, As + c * 8);
      GLD_LDS(Bt + (size_t)(n0 + row) * K + kt + ko, Bs + c * 8);
    }
    __syncthreads();
#pragma unroll
    for (int ks = 0; ks < 64; ks += 32) {
      bf16x8 av[4], bv[4];
#pragma unroll
      for (int mi = 0; mi < 4; ++mi)
        av[mi] = *(const bf16x8*)&As[(wr * 64 + mi * 16 + lrow) * 64 + ks + lk];
#pragma unroll
      for (int ni = 0; ni < 4; ++ni)
        bv[ni] = *(const bf16x8*)&Bs[(wc * 64 + ni * 16 + lrow) * 64 + ks + lk];
#pragma unroll
      for (int mi = 0; mi < 4; ++mi)
#pragma unroll
        for (int ni = 0; ni < 4; ++ni)
          acc[mi][ni] = __builtin_amdgcn_mfma_f32_16x16x32_bf16(
              av[mi], bv[ni], acc[mi][ni], 0, 0, 0);
    }
  }

  const int rbase = m0 + wr * 64 + (lane >> 4) * 4;
  const int cbase = n0 + wc * 64 + (lane & 15);
#pragma unroll
  for (int mi = 0; mi < 4; ++mi)
#pragma unroll
    for (int ni = 0; ni < 4; ++ni)
#pragma unroll
      for (int r = 0; r < 4; ++r)
        C[(size_t)(rbase + mi * 16 + r) * ldc + cbase + ni * 16] =
            (__bf16)acc[mi][ni][r];
}

// ---------------- 4. band attention v3: MFMA flash-style -------------------
// Block = (64-query tile, h, b); 512 blocks; 4 waves, wave w -> 16 queries.
// All LDS tiles XOR-swizzled: byte_in_row ^= (row&7)<<4.
//   Qs [64][64]b  Ks [128][64]b  Ls [80][64]b  VTs [64][192]b (keys>=128 = 0)
//   Ps: per-wave [16] rows x 256B, holds QE (cols 0..79) then P (cols 0..95).
// Wave w's key window: jc in [16w, 16w+79] (band => 5 n-tiles).
__global__ __launch_bounds__(256) void attn_band_v3(
    const __bf16* __restrict__ QKV,  // [2048][3072]: Q | K | V
    const float* __restrict__ lut,   // [2047][64]
    __bf16* __restrict__ Ctx) {      // [2048][1024]
  __shared__ alignas(16) __bf16 Qs[64 * 64];     // 8 KB
  __shared__ alignas(16) __bf16 Ks[128 * 64];    // 16 KB
  __shared__ alignas(16) __bf16 Ls[80 * 64];     // 10 KB
  __shared__ alignas(16) __bf16 VTs[64 * 192];   // 24 KB
  __shared__ alignas(16) __bf16 Ps[4 * 16 * 128];// 16 KB (4KB per wave)

  const int tid = threadIdx.x;
  const int i0 = blockIdx.x * 64;
  const int h = blockIdx.y;
  const int b = blockIdx.z;
  const size_t base = (size_t)b * 1024 * 3072 + (size_t)h * 64;

  // ---- staging (all writes swizzled) ----
  for (int c = tid; c < 512; c += 256) {  // Q: 64 rows x 8 chunks
    const int row = c >> 3, kb = (c & 7) * 16;
    bf16x8 v = *(const bf16x8*)(QKV + base + (size_t)(i0 + row) * 3072 + (c & 7) * 8);
    *(bf16x8*)((char*)Qs + row * 128 + (kb ^ ((row & 7) << 4))) = v;
  }
  for (int c = tid; c < 1024; c += 256) {  // K: 128 rows x 8 chunks
    const int row = c >> 3, kb = (c & 7) * 16;
    int j = i0 - 32 + row;
    j = j < 0 ? 0 : (j > 1023 ? 1023 : j);
    bf16x8 v = *(const bf16x8*)(QKV + base + (size_t)j * 3072 + 1024 + (c & 7) * 8);
    *(bf16x8*)((char*)Ks + row * 128 + (kb ^ ((row & 7) << 4))) = v;
  }
  for (int c = tid; c < 1152; c += 256) {  // V -> VT: 144 keys x 8 d-chunks
    const int key = c >> 3, d0 = (c & 7) * 8;
    bf16x8 v;
    if (key < 128) {
      int j = i0 - 32 + key;
      j = j < 0 ? 0 : (j > 1023 ? 1023 : j);
      v = *(const bf16x8*)(QKV + base + (size_t)j * 3072 + 2048 + d0);
    } else {
      v = bf16x8{};  // zero pad keys 128..143 (read by padded P cols)
    }
#pragma unroll
    for (int e = 0; e < 8; ++e) {
      const int row = d0 + e;
      *(__bf16*)((char*)VTs + row * 384 + ((2 * key) ^ ((row & 7) << 4))) = v[e];
    }
  }
  for (int c = tid; c < 640; c += 256) {  // L: rows 0..64 real, 65..79 zero
    const int row = c >> 3, d0 = (c & 7) * 8;
    bf16x8 o;
    if (row < 65) {
      const float* src = lut + (size_t)(991 + row) * 64 + d0;
#pragma unroll
      for (int e = 0; e < 8; ++e) o[e] = (__bf16)src[e];
    } else {
      o = bf16x8{};
    }
    *(bf16x8*)((char*)Ls + row * 128 + ((2 * d0) ^ ((row & 7) << 4))) = o;
  }
  __syncthreads();

  const int w = tid >> 6, lane = tid & 63;
  const int lr = lane & 15, lk = lane >> 4;
  char* Pw = (char*)(Ps + w * 16 * 128);  // [16 rows][256B]

  // ---- Q A-fragments ----
  bf16x8 aq[2];
  {
    const int row = w * 16 + lr, swz = (row & 7) << 4;
#pragma unroll
    for (int ks = 0; ks < 2; ++ks)
      aq[ks] = *(const bf16x8*)((const char*)Qs + row * 128 + ((ks * 64 + lk * 16) ^ swz));
  }

  // ---- S = Q.K^T and QE = Q.L^T (5 n-tiles each) ----
  f32x4 accs[5] = {};
  f32x4 accq[5] = {};
#pragma unroll
  for (int n = 0; n < 5; ++n) {
    const int krow = (w + n) * 16 + lr, ksz = (krow & 7) << 4;
    const int lrow = n * 16 + lr, lsz = (lrow & 7) << 4;
#pragma unroll
    for (int ks = 0; ks < 2; ++ks) {
      bf16x8 bk = *(const bf16x8*)((const char*)Ks + krow * 128 + ((ks * 64 + lk * 16) ^ ksz));
      accs[n] = __builtin_amdgcn_mfma_f32_16x16x32_bf16(aq[ks], bk, accs[n], 0, 0, 0);
      bf16x8 bl = *(const bf16x8*)((const char*)Ls + lrow * 128 + ((ks * 64 + lk * 16) ^ lsz));
      accq[n] = __builtin_amdgcn_mfma_f32_16x16x32_bf16(aq[ks], bl, accq[n], 0, 0, 0);
    }
  }

  // ---- QE -> per-wave LDS (bf16, cols 0..79) ----
#pragma unroll
  for (int n = 0; n < 5; ++n)
#pragma unroll
    for (int r = 0; r < 4; ++r) {
      const int row = lk * 4 + r, col = n * 16 + lr;
      *(__bf16*)(Pw + row * 256 + ((2 * col) ^ ((row & 7) << 4))) = (__bf16)accq[n][r];
    }
  __syncthreads();

  // ---- combine skew + mask + softmax (wave-parallel, 4 rows per lane) ----
  float p[5][4], linv[4];
  {
    float sv[5][4], mrow[4], lsum[4];
#pragma unroll
    for (int reg = 0; reg < 4; ++reg) mrow[reg] = -1e30f;
#pragma unroll
    for (int n = 0; n < 5; ++n)
#pragma unroll
      for (int reg = 0; reg < 4; ++reg) {
        const int row = lk * 4 + reg;
        const int iq = w * 16 + row;
        const int jc = (w + n) * 16 + lr;
        const int r = jc - iq;              // relative key, band = [0,64]
        const int j = i0 - 32 + jc;
        const int rc = r < 0 ? 0 : (r > 64 ? 64 : r);
        const float qe = (float)*(const __bf16*)(Pw + row * 256 + ((2 * rc) ^ ((row & 7) << 4)));
        const bool valid = (r >= 0) & (r <= 64) & (j >= 0) & (j <= 1023);
        const float s = valid ? (accs[n][reg] + qe) * 0.125f : -1e30f;
        sv[n][reg] = s;
        mrow[reg] = fmaxf(mrow[reg], s);
      }
#pragma unroll
    for (int reg = 0; reg < 4; ++reg) {
#pragma unroll
      for (int off = 1; off < 16; off <<= 1)
        mrow[reg] = fmaxf(mrow[reg], __shfl_xor(mrow[reg], off));
      lsum[reg] = 0.f;
    }
#pragma unroll
    for (int n = 0; n < 5; ++n)
#pragma unroll
      for (int reg = 0; reg < 4; ++reg) {
        const float e = __expf(sv[n][reg] - mrow[reg]);
        p[n][reg] = e;
        lsum[reg] += e;
      }
#pragma unroll
    for (int reg = 0; reg < 4; ++reg) {
#pragma unroll
      for (int off = 1; off < 16; off <<= 1)
        lsum[reg] += __shfl_xor(lsum[reg], off);
      linv[reg] = 1.0f / lsum[reg];
    }
  }

  // ---- P -> LDS (bf16, cols 0..79; zero cols 80..95) ----
#pragma unroll
  for (int n = 0; n < 5; ++n)
#pragma unroll
    for (int r = 0; r < 4; ++r) {
      const int row = lk * 4 + r, col = n * 16 + lr;
      *(__bf16*)(Pw + row * 256 + ((2 * col) ^ ((row & 7) << 4))) = (__bf16)p[n][r];
    }
  *(uint2*)(Pw + lr * 256 + ((160 + lk * 8) ^ ((lr & 7) << 4))) = make_uint2(0u, 0u);
  __syncthreads();

  // ---- PV: ctx[16][64] = P[16][96] @ V[96-key window][64] ----
  f32x4 acco[4] = {};
  bf16x8 ap[3];
  {
    const int row = lr, swz = (row & 7) << 4;
#pragma unroll
    for (int ks = 0; ks < 3; ++ks)
      ap[ks] = *(const bf16x8*)(Pw + row * 256 + ((ks * 64 + lk * 16) ^ swz));
  }
#pragma unroll
  for (int n = 0; n < 4; ++n) {
    const int vrow = n * 16 + lr, swz = (vrow & 7) << 4;
#pragma unroll
    for (int ks = 0; ks < 3; ++ks) {
      bf16x8 bv = *(const bf16x8*)((const char*)VTs + vrow * 384 +
                                   ((32 * w + ks * 64 + lk * 16) ^ swz));
      acco[n] = __builtin_amdgcn_mfma_f32_16x16x32_bf16(ap[ks], bv, acco[n], 0, 0, 0);
    }
  }

  // ---- output ----
#pragma unroll
  for (int n = 0; n < 4; ++n)
#pragma unroll
    for (int reg = 0; reg < 4; ++reg) {
      const int row = lk * 4 + reg;
      const int i = i0 + w * 16 + row;
      const int d = n * 16 + lr;
      Ctx[(size_t)(b * 1024 + i) * 1024 + h * 64 + d] = (__bf16)(acco[n][reg] * linv[reg]);
    }
}

// ---------------- 6. residual + bias + LayerNorm ---------------------------
__global__ __launch_bounds__(256) void ln_residual(
    const float* __restrict__ x, const __bf16* __restrict__ outb,
    const float* __restrict__ bout, const float* __restrict__ gamma,
    const float* __restrict__ beta, float* __restrict__ y) {
  const int r = blockIdx.x;
  const int tid = threadIdx.x;
  float v[4];
  float s = 0.f, ss = 0.f;
#pragma unroll
  for (int it = 0; it < 4; ++it) {
    const int d = it * 256 + tid;
    const float t = x[(size_t)r * 1024 + d] + (float)outb[(size_t)r * 1024 + d] + bout[d];
    v[it] = t;
    s += t;
    ss += t * t;
  }
#pragma unroll
  for (int off = 32; off; off >>= 1) {
    s += __shfl_xor(s, off);
    ss += __shfl_xor(ss, off);
  }
  __shared__ float red[8];
  const int w = tid >> 6, lane = tid & 63;
  if (lane == 0) { red[w] = s; red[4 + w] = ss; }
  __syncthreads();
  s = red[0] + red[1] + red[2] + red[3];
  ss = red[4] + red[5] + red[6] + red[7];
  const float mu = s * (1.f / 1024.f);
  const float var = ss * (1.f / 1024.f) - mu * mu;
  const float rs = rsqrtf(var + 1e-5f);
#pragma unroll
  for (int it = 0; it < 4; ++it) {
    const int d = it * 256 + tid;
    y[(size_t)r * 1024 + d] = (v[it] - mu) * rs * gamma[d] + beta[d];
  }
}

// ---------------------------------------------------------------------------
extern "C" void kernel_launch(void* const* d_in, const int* in_sizes, int n_in,
                              void* d_out, int out_size, void* d_ws, size_t ws_size,
                              hipStream_t stream) {
  const float* x     = (const float*)d_in[0];
  const float* ctxin = (const float*)d_in[1];
  const float* lut   = (const float*)d_in[2];
  const float* Wq    = (const float*)d_in[3];
  const float* Wk    = (const float*)d_in[4];
  const float* Wv    = (const float*)d_in[5];
  const float* Wo    = (const float*)d_in[6];
  const float* bo    = (const float*)d_in[7];
  const float* gam   = (const float*)d_in[8];
  const float* bet   = (const float*)d_in[9];
  float* out = (float*)d_out;

  char* ws = (char*)d_ws;
  __bf16* Xb    = (__bf16*)(ws);                        // 4 MB  [2048][1024]
  __bf16* Cb    = (__bf16*)(ws + ((size_t)4 << 20));    // 4 MB  [2048][1024]
  __bf16* Wqkvt = (__bf16*)(ws + ((size_t)8 << 20));    // 6 MB  [3072][1024]
  __bf16* Wot   = (__bf16*)(ws + ((size_t)14 << 20));   // 2 MB  [1024][1024]
  __bf16* QKVb  = (__bf16*)(ws + ((size_t)16 << 20));   // 12 MB [2048][3072]
  __bf16* CtxB  = (__bf16*)(ws + ((size_t)28 << 20));   // 4 MB  [2048][1024]
  __bf16* OutB  = (__bf16*)(ws + ((size_t)32 << 20));   // 4 MB  [2048][1024]

  cvt2_f32_bf16<<<dim3(2048, 2), 256, 0, stream>>>(x, ctxin, Xb, Cb);
  transpose4_cvt<<<dim3(16, 16, 4), 256, 0, stream>>>(Wq, Wk, Wv, Wo, Wqkvt, Wot);

  // fused QKV projection: cols<1024 from Xb, cols>=1024 from Cb
  gemm_bf16<<<dim3(24, 16), 256, 0, stream>>>(Xb, Cb, 1024, Wqkvt, QKVb, 1024, 3072);

  attn_band_v3<<<dim3(16, 16, 2), 256, 0, stream>>>(QKVb, lut, CtxB);

  gemm_bf16<<<dim3(8, 16), 256, 0, stream>>>(CtxB, CtxB, 0, Wot, OutB, 1024, 1024);

  ln_residual<<<2048, 256, 0, stream>>>(x, OutB, bo, gam, bet, out);
}

// Round 6
// 82.170 us; speedup vs baseline: 3.2674x; 1.0591x over previous
//
#include <hip/hip_runtime.h>
#include <hip/hip_bf16.h>
#include <cstdint>

// ---------------------------------------------------------------------------
// LocalMultiHeadAttention: B=2, T=1024, D=1024, H=16, dh=64, band=65 (half 32)
// BISECTION ROUND: R4/R5 failed with identical absmax 0.398 (deterministic).
// Suspect set = {prep fusion, packed-V staging, templated gemm BM=64}.
// This round: prep + packed-V reverted to R3-exact; ONLY the templated gemm
// (BM=64 out-proj) is kept. BM=128 instantiation is bit-identical to R3.
//   1. cvt2: x, context -> bf16
//   2. transpose4: weights -> Wqkvt / Wot
//   3. gemm<128>: QKVb = {Xb@Wq^T | Cb@Wk^T | Cb@Wv^T}
//   4. attn v3 (R3-exact): MFMA band attention
//   5. gemm<64>: OutB = CtxB @ Wot^T (256 blocks -> all CUs)
//   6. LN (vectorized): y = LayerNorm(x + OutB + b_out)
// ---------------------------------------------------------------------------

typedef __bf16 bf16x8 __attribute__((ext_vector_type(8)));
typedef __bf16 bf16x4 __attribute__((ext_vector_type(4)));
typedef float f32x4 __attribute__((ext_vector_type(4)));

#define GLD_LDS(gptr, lptr)                                                    \
  __builtin_amdgcn_global_load_lds(                                            \
      (const __attribute__((address_space(1))) void*)(gptr),                   \
      (__attribute__((address_space(3))) void*)(lptr), 16, 0, 0)

// ---------------- 1. f32 -> bf16 convert (x and context fused) [R3-exact] --
__global__ __launch_bounds__(256) void cvt2_f32_bf16(
    const float* __restrict__ x, const float* __restrict__ c,
    __bf16* __restrict__ X, __bf16* __restrict__ C) {
  const float* in = blockIdx.y ? c : x;
  __bf16* out = blockIdx.y ? C : X;
  const int i = blockIdx.x * 256 + threadIdx.x;  // 2048*256 == 524288 exactly
  float4 v = ((const float4*)in)[i];
  bf16x4 o;
  o[0] = (__bf16)v.x; o[1] = (__bf16)v.y; o[2] = (__bf16)v.z; o[3] = (__bf16)v.w;
  ((bf16x4*)out)[i] = o;
}

// ---------------- 2. transpose + convert, 4 weights [R3-exact] -------------
__global__ __launch_bounds__(256) void transpose4_cvt(
    const float* __restrict__ Wq, const float* __restrict__ Wk,
    const float* __restrict__ Wv, const float* __restrict__ Wo,
    __bf16* __restrict__ Wqkvt, __bf16* __restrict__ Wot) {
  const int z = blockIdx.z;
  const float* W = z == 0 ? Wq : z == 1 ? Wk : z == 2 ? Wv : Wo;
  __bf16* Wt = (z == 3) ? Wot : Wqkvt + (size_t)z * 1024 * 1024;
  __shared__ float tile[64][65];
  const int k0 = blockIdx.x * 64, n0 = blockIdx.y * 64;
  const int tx = threadIdx.x & 63, ty = threadIdx.x >> 6;
#pragma unroll
  for (int r = ty; r < 64; r += 4)
    tile[r][tx] = W[(size_t)(k0 + r) * 1024 + n0 + tx];
  __syncthreads();
#pragma unroll
  for (int r = ty; r < 64; r += 4)
    Wt[(size_t)(n0 + r) * 1024 + k0 + tx] = (__bf16)tile[tx][r];
}

// ---------------- 3/5. bf16 GEMM, templated BM (R3 staging structure) ------
// BM x 128 tile, BK=64, 4 waves (2x2), mfma 16x16x32, global_load_lds w16.
// For BM=128 this is bit-identical to R3's proven kernel; BM=64 only
// predicates the A-side GLD with a wave-uniform row<BM test.
template <int BM>
__global__ __launch_bounds__(256) void gemm_bf16(
    const __bf16* __restrict__ A0, const __bf16* __restrict__ A1, int nsplit,
    const __bf16* __restrict__ Bt, __bf16* __restrict__ C, int K, int ldc) {
  constexpr int MR = BM / 32;  // acc rows per wave (wave grid is 2x2)
  __shared__ alignas(16) __bf16 As[BM * 64];
  __shared__ alignas(16) __bf16 Bs[128 * 64];
  const int tid = threadIdx.x;
  const int m0 = blockIdx.y * BM, n0 = blockIdx.x * 128;
  const __bf16* A = (n0 < nsplit) ? A0 : A1;
  const int w = tid >> 6, lane = tid & 63;
  const int wr = w >> 1, wc = w & 1;
  const int lrow = lane & 15, lk = (lane >> 4) * 8;

  f32x4 acc[MR][4] = {};

  for (int kt = 0; kt < K; kt += 64) {
    __syncthreads();
#pragma unroll
    for (int it = 0; it < 4; ++it) {
      const int c = it * 256 + tid;          // 0..1023 chunk id (16B each)
      const int row = c >> 3;                // 0..127
      const int ko = (c & 7) * 8;            // 0..56
      if (row < BM)  // wave-uniform; always true for BM=128 (== R3)
        GLD_LDS(A + (size_t)(m0 + row) * K + kt + ko, As + c * 8);
      GLD_LDS(Bt + (size_t)(n0 + row) * K + kt + ko, Bs + c * 8);
    }
    __syncthreads();
#pragma unroll
    for (int ks = 0; ks < 64; ks += 32) {
      bf16x8 av[MR], bv[4];
#pragma unroll
      for (int mi = 0; mi < MR; ++mi)
        av[mi] = *(const bf16x8*)&As[(wr * (MR * 16) + mi * 16 + lrow) * 64 + ks + lk];
#pragma unroll
      for (int ni = 0; ni < 4; ++ni)
        bv[ni] = *(const bf16x8*)&Bs[(wc * 64 + ni * 16 + lrow) * 64 + ks + lk];
#pragma unroll
      for (int mi = 0; mi < MR; ++mi)
#pragma unroll
        for (int ni = 0; ni < 4; ++ni)
          acc[mi][ni] = __builtin_amdgcn_mfma_f32_16x16x32_bf16(
              av[mi], bv[ni], acc[mi][ni], 0, 0, 0);
    }
  }

  const int rbase = m0 + wr * (MR * 16) + (lane >> 4) * 4;
  const int cbase = n0 + wc * 64 + (lane & 15);
#pragma unroll
  for (int mi = 0; mi < MR; ++mi)
#pragma unroll
    for (int ni = 0; ni < 4; ++ni)
#pragma unroll
      for (int r = 0; r < 4; ++r)
        C[(size_t)(rbase + mi * 16 + r) * ldc + cbase + ni * 16] =
            (__bf16)acc[mi][ni][r];
}

// ---------------- 4. band attention v3 [R3-exact, unpacked V] --------------
__global__ __launch_bounds__(256) void attn_band_v3(
    const __bf16* __restrict__ QKV,  // [2048][3072]: Q | K | V
    const float* __restrict__ lut,   // [2047][64]
    __bf16* __restrict__ Ctx) {      // [2048][1024]
  __shared__ alignas(16) __bf16 Qs[64 * 64];
  __shared__ alignas(16) __bf16 Ks[128 * 64];
  __shared__ alignas(16) __bf16 Ls[80 * 64];
  __shared__ alignas(16) __bf16 VTs[64 * 192];
  __shared__ alignas(16) __bf16 Ps[4 * 16 * 128];

  const int tid = threadIdx.x;
  const int i0 = blockIdx.x * 64;
  const int h = blockIdx.y;
  const int b = blockIdx.z;
  const size_t base = (size_t)b * 1024 * 3072 + (size_t)h * 64;

  // ---- staging ----
  for (int c = tid; c < 512; c += 256) {  // Q
    const int row = c >> 3, kb = (c & 7) * 16;
    bf16x8 v = *(const bf16x8*)(QKV + base + (size_t)(i0 + row) * 3072 + (c & 7) * 8);
    *(bf16x8*)((char*)Qs + row * 128 + (kb ^ ((row & 7) << 4))) = v;
  }
  for (int c = tid; c < 1024; c += 256) {  // K
    const int row = c >> 3, kb = (c & 7) * 16;
    int j = i0 - 32 + row;
    j = j < 0 ? 0 : (j > 1023 ? 1023 : j);
    bf16x8 v = *(const bf16x8*)(QKV + base + (size_t)j * 3072 + 1024 + (c & 7) * 8);
    *(bf16x8*)((char*)Ks + row * 128 + (kb ^ ((row & 7) << 4))) = v;
  }
  for (int c = tid; c < 1152; c += 256) {  // V -> VT (R3-exact scalar writes)
    const int key = c >> 3, d0 = (c & 7) * 8;
    bf16x8 v;
    if (key < 128) {
      int j = i0 - 32 + key;
      j = j < 0 ? 0 : (j > 1023 ? 1023 : j);
      v = *(const bf16x8*)(QKV + base + (size_t)j * 3072 + 2048 + d0);
    } else {
      v = bf16x8{};  // zero pad keys 128..143
    }
#pragma unroll
    for (int e = 0; e < 8; ++e) {
      const int row = d0 + e;
      *(__bf16*)((char*)VTs + row * 384 + ((2 * key) ^ ((row & 7) << 4))) = v[e];
    }
  }
  for (int c = tid; c < 640; c += 256) {  // L rows 0..64 real, 65..79 zero
    const int row = c >> 3, d0 = (c & 7) * 8;
    bf16x8 o;
    if (row < 65) {
      const float* src = lut + (size_t)(991 + row) * 64 + d0;
#pragma unroll
      for (int e = 0; e < 8; ++e) o[e] = (__bf16)src[e];
    } else {
      o = bf16x8{};
    }
    *(bf16x8*)((char*)Ls + row * 128 + ((2 * d0) ^ ((row & 7) << 4))) = o;
  }
  __syncthreads();

  const int w = tid >> 6, lane = tid & 63;
  const int lr = lane & 15, lk = lane >> 4;
  char* Pw = (char*)(Ps + w * 16 * 128);

  bf16x8 aq[2];
  {
    const int row = w * 16 + lr, swz = (row & 7) << 4;
#pragma unroll
    for (int ks = 0; ks < 2; ++ks)
      aq[ks] = *(const bf16x8*)((const char*)Qs + row * 128 + ((ks * 64 + lk * 16) ^ swz));
  }

  // ---- S = Q.K^T and QE = Q.L^T ----
  f32x4 accs[5] = {};
  f32x4 accq[5] = {};
#pragma unroll
  for (int n = 0; n < 5; ++n) {
    const int krow = (w + n) * 16 + lr, ksz = (krow & 7) << 4;
    const int lrow = n * 16 + lr, lsz = (lrow & 7) << 4;
#pragma unroll
    for (int ks = 0; ks < 2; ++ks) {
      bf16x8 bk = *(const bf16x8*)((const char*)Ks + krow * 128 + ((ks * 64 + lk * 16) ^ ksz));
      accs[n] = __builtin_amdgcn_mfma_f32_16x16x32_bf16(aq[ks], bk, accs[n], 0, 0, 0);
      bf16x8 bl = *(const bf16x8*)((const char*)Ls + lrow * 128 + ((ks * 64 + lk * 16) ^ lsz));
      accq[n] = __builtin_amdgcn_mfma_f32_16x16x32_bf16(aq[ks], bl, accq[n], 0, 0, 0);
    }
  }

  // ---- QE -> per-wave LDS ----
#pragma unroll
  for (int n = 0; n < 5; ++n)
#pragma unroll
    for (int r = 0; r < 4; ++r) {
      const int row = lk * 4 + r, col = n * 16 + lr;
      *(__bf16*)(Pw + row * 256 + ((2 * col) ^ ((row & 7) << 4))) = (__bf16)accq[n][r];
    }
  __syncthreads();

  // ---- combine skew + mask + softmax ----
  float p[5][4], linv[4];
  {
    float sv[5][4], mrow[4], lsum[4];
#pragma unroll
    for (int reg = 0; reg < 4; ++reg) mrow[reg] = -1e30f;
#pragma unroll
    for (int n = 0; n < 5; ++n)
#pragma unroll
      for (int reg = 0; reg < 4; ++reg) {
        const int row = lk * 4 + reg;
        const int iq = w * 16 + row;
        const int jc = (w + n) * 16 + lr;
        const int r = jc - iq;
        const int j = i0 - 32 + jc;
        const int rc = r < 0 ? 0 : (r > 64 ? 64 : r);
        const float qe = (float)*(const __bf16*)(Pw + row * 256 + ((2 * rc) ^ ((row & 7) << 4)));
        const bool valid = (r >= 0) & (r <= 64) & (j >= 0) & (j <= 1023);
        const float s = valid ? (accs[n][reg] + qe) * 0.125f : -1e30f;
        sv[n][reg] = s;
        mrow[reg] = fmaxf(mrow[reg], s);
      }
#pragma unroll
    for (int reg = 0; reg < 4; ++reg) {
#pragma unroll
      for (int off = 1; off < 16; off <<= 1)
        mrow[reg] = fmaxf(mrow[reg], __shfl_xor(mrow[reg], off));
      lsum[reg] = 0.f;
    }
#pragma unroll
    for (int n = 0; n < 5; ++n)
#pragma unroll
      for (int reg = 0; reg < 4; ++reg) {
        const float e = __expf(sv[n][reg] - mrow[reg]);
        p[n][reg] = e;
        lsum[reg] += e;
      }
#pragma unroll
    for (int reg = 0; reg < 4; ++reg) {
#pragma unroll
      for (int off = 1; off < 16; off <<= 1)
        lsum[reg] += __shfl_xor(lsum[reg], off);
      linv[reg] = 1.0f / lsum[reg];
    }
  }

  // ---- P -> LDS ----
#pragma unroll
  for (int n = 0; n < 5; ++n)
#pragma unroll
    for (int r = 0; r < 4; ++r) {
      const int row = lk * 4 + r, col = n * 16 + lr;
      *(__bf16*)(Pw + row * 256 + ((2 * col) ^ ((row & 7) << 4))) = (__bf16)p[n][r];
    }
  *(uint2*)(Pw + lr * 256 + ((160 + lk * 8) ^ ((lr & 7) << 4))) = make_uint2(0u, 0u);
  __syncthreads();

  // ---- PV ----
  f32x4 acco[4] = {};
  bf16x8 ap[3];
  {
    const int row = lr, swz = (row & 7) << 4;
#pragma unroll
    for (int ks = 0; ks < 3; ++ks)
      ap[ks] = *(const bf16x8*)(Pw + row * 256 + ((ks * 64 + lk * 16) ^ swz));
  }
#pragma unroll
  for (int n = 0; n < 4; ++n) {
    const int vrow = n * 16 + lr, swz = (vrow & 7) << 4;
#pragma unroll
    for (int ks = 0; ks < 3; ++ks) {
      bf16x8 bv = *(const bf16x8*)((const char*)VTs + vrow * 384 +
                                   ((32 * w + ks * 64 + lk * 16) ^ swz));
      acco[n] = __builtin_amdgcn_mfma_f32_16x16x32_bf16(ap[ks], bv, acco[n], 0, 0, 0);
    }
  }

#pragma unroll
  for (int n = 0; n < 4; ++n)
#pragma unroll
    for (int reg = 0; reg < 4; ++reg) {
      const int row = lk * 4 + reg;
      const int i = i0 + w * 16 + row;
      const int d = n * 16 + lr;
      Ctx[(size_t)(b * 1024 + i) * 1024 + h * 64 + d] = (__bf16)(acco[n][reg] * linv[reg]);
    }
}

// ---------------- 6. residual + bias + LayerNorm (vectorized) --------------
__global__ __launch_bounds__(256) void ln_residual(
    const float* __restrict__ x, const __bf16* __restrict__ outb,
    const float* __restrict__ bout, const float* __restrict__ gamma,
    const float* __restrict__ beta, float* __restrict__ y) {
  const int r = blockIdx.x;
  const int tid = threadIdx.x;
  const int d0 = tid * 4;
  const size_t rb = (size_t)r * 1024 + d0;
  float4 xv = *(const float4*)(x + rb);
  bf16x4 ov = *(const bf16x4*)(outb + rb);
  float4 bv = *(const float4*)(bout + d0);
  float v0 = xv.x + (float)ov[0] + bv.x;
  float v1 = xv.y + (float)ov[1] + bv.y;
  float v2 = xv.z + (float)ov[2] + bv.z;
  float v3 = xv.w + (float)ov[3] + bv.w;
  float s = v0 + v1 + v2 + v3;
  float ss = v0 * v0 + v1 * v1 + v2 * v2 + v3 * v3;
#pragma unroll
  for (int off = 32; off; off >>= 1) {
    s += __shfl_xor(s, off);
    ss += __shfl_xor(ss, off);
  }
  __shared__ float red[8];
  const int w = tid >> 6, lane = tid & 63;
  if (lane == 0) { red[w] = s; red[4 + w] = ss; }
  __syncthreads();
  s = red[0] + red[1] + red[2] + red[3];
  ss = red[4] + red[5] + red[6] + red[7];
  const float mu = s * (1.f / 1024.f);
  const float var = ss * (1.f / 1024.f) - mu * mu;
  const float rs = rsqrtf(var + 1e-5f);
  float4 gv = *(const float4*)(gamma + d0);
  float4 bev = *(const float4*)(beta + d0);
  float4 o;
  o.x = (v0 - mu) * rs * gv.x + bev.x;
  o.y = (v1 - mu) * rs * gv.y + bev.y;
  o.z = (v2 - mu) * rs * gv.z + bev.z;
  o.w = (v3 - mu) * rs * gv.w + bev.w;
  *(float4*)(y + rb) = o;
}

// ---------------------------------------------------------------------------
extern "C" void kernel_launch(void* const* d_in, const int* in_sizes, int n_in,
                              void* d_out, int out_size, void* d_ws, size_t ws_size,
                              hipStream_t stream) {
  const float* x     = (const float*)d_in[0];
  const float* ctxin = (const float*)d_in[1];
  const float* lut   = (const float*)d_in[2];
  const float* Wq    = (const float*)d_in[3];
  const float* Wk    = (const float*)d_in[4];
  const float* Wv    = (const float*)d_in[5];
  const float* Wo    = (const float*)d_in[6];
  const float* bo    = (const float*)d_in[7];
  const float* gam   = (const float*)d_in[8];
  const float* bet   = (const float*)d_in[9];
  float* out = (float*)d_out;

  char* ws = (char*)d_ws;
  __bf16* Xb    = (__bf16*)(ws);                        // 4 MB  [2048][1024]
  __bf16* Cb    = (__bf16*)(ws + ((size_t)4 << 20));    // 4 MB  [2048][1024]
  __bf16* Wqkvt = (__bf16*)(ws + ((size_t)8 << 20));    // 6 MB  [3072][1024]
  __bf16* Wot   = (__bf16*)(ws + ((size_t)14 << 20));   // 2 MB  [1024][1024]
  __bf16* QKVb  = (__bf16*)(ws + ((size_t)16 << 20));   // 12 MB [2048][3072]
  __bf16* CtxB  = (__bf16*)(ws + ((size_t)28 << 20));   // 4 MB  [2048][1024]
  __bf16* OutB  = (__bf16*)(ws + ((size_t)32 << 20));   // 4 MB  [2048][1024]

  cvt2_f32_bf16<<<dim3(2048, 2), 256, 0, stream>>>(x, ctxin, Xb, Cb);
  transpose4_cvt<<<dim3(16, 16, 4), 256, 0, stream>>>(Wq, Wk, Wv, Wo, Wqkvt, Wot);

  // fused QKV projection: cols<1024 from Xb, cols>=1024 from Cb
  gemm_bf16<128><<<dim3(24, 16), 256, 0, stream>>>(Xb, Cb, 1024, Wqkvt, QKVb,
                                                   1024, 3072);

  attn_band_v3<<<dim3(16, 16, 2), 256, 0, stream>>>(QKVb, lut, CtxB);

  gemm_bf16<64><<<dim3(8, 32), 256, 0, stream>>>(CtxB, CtxB, 0, Wot, OutB,
                                                 1024, 1024);

  ln_residual<<<2048, 256, 0, stream>>>(x, OutB, bo, gam, bet, out);
}